// Round 1
// baseline (975.113 us; speedup 1.0000x reference)
//
#include <hip/hip_runtime.h>

// SimpleCRA round 6: 256x256-tile double-buffered GEMM (T1+T2+T4+T5).
// Same virtual-K split-bf16 math (dot = ah*bh + al*bh + ah*bl, K'=1536) with
// identical accumulation order => bitwise-identical scores to round 5, so the
// EPS/tie-recheck path is unchanged. New GEMM structure:
//   - 1024 blocks (128 mb x 8 colb, bijective XCD swizzle), 512 thr / 8 waves
//   - per-wave 128x64 output (8x4 frags of 16x16x32), BK=64, 24 K-tiles
//   - LDS 128 KiB: 2 buffers x (A 32K + B 32K); 1 block/CU
//   - counted s_waitcnt vmcnt(8): tile t's 8 DMA issued one full iter ahead
//   - LDS XOR swizzle (3 row bits -> byte bits 4-6) baked into the packed
//     images (linear global_load_lds dest + pre-swizzled source + swizzled
//     ds_read) => 2-way (free) bank aliasing instead of 16-way.

#define D_DIM    512
#define K_CODES  2048
#define N_ROWS   32768
#define EPS_GAP  1e-5f
#define LOSS_SCALE (1.0f / 16777216.0f)   // 1/(N_ROWS*D_DIM)

typedef __attribute__((ext_vector_type(8))) short short8;   // 8 bf16 (4 VGPR)
typedef __attribute__((ext_vector_type(4))) float f32x4;    // MFMA C/D

// XOR swizzle on byte offset within a [128 rows][64 k] bf16 half-image
// (row = L>>7): bits 4-6 ^= {row bit1->4, row bit2->5, row bit0->6}.
// Involution; 16-B granularity preserved (bits 0-3 untouched).
#define SWZ(L) ((L) ^ (((L) >> 1) & 0x40) ^ (((L) >> 4) & 0x30))

__device__ __forceinline__ void split_bf16(float f, unsigned short& h, unsigned short& l) {
    unsigned u = __float_as_uint(f);
    h = (unsigned short)(u >> 16);                       // truncation split
    float hr = __uint_as_float(u & 0xFFFF0000u);
    l = (unsigned short)(__float_as_uint(f - hr) >> 16);
}

// async global->LDS DMA, 16 B/lane; lds ptr wave-uniform, HW adds lane*16.
__device__ __forceinline__ void dma16(const void* g, void* l) {
    __builtin_amdgcn_global_load_lds(
        (const __attribute__((address_space(1))) unsigned int*)g,
        (__attribute__((address_space(3))) unsigned int*)l, 16, 0, 0);
}

// insert candidate into sorted-2 list ordered by (val, idx) — total order,
// merge-order independent; matches numpy first-occurrence argmin.
__device__ __forceinline__ void merge_cand(float s, int idx, float& v1, int& i1, float& v2, int& i2) {
    if (s < v1 || (s == v1 && idx < i1)) { v2 = v1; i2 = i1; v1 = s; i1 = idx; }
    else if (s < v2 || (s == v2 && idx < i2)) { v2 = s; i2 = idx; }
}

// ---------------------------------------------------------------------------
// Kernel 1: pack A' images, swizzled.
// Layout: [mb256 128][atile 16][half 2][swizzled [128][64]] shorts.
// atile 0-7 = ah of d in [64j,64j+64); atile 8-15 = al of same d ranges.
// Block = 128 mean-rows (= one half-image of every atile). 256 blocks.
// ---------------------------------------------------------------------------
__global__ __launch_bounds__(256, 1)
void cra_pack_a(const float* __restrict__ ce,
                unsigned short* __restrict__ Ap)
{
    const int tid   = threadIdx.x;
    const int mb128 = blockIdx.x;        // 0..255
    const int mb256 = mb128 >> 1;
    const int half  = mb128 & 1;
    const int rq = tid >> 5;             // row slice 0..7
    const int dq = tid & 31;             // 16-float span index
    const int d0 = dq * 16;
    const int j  = dq >> 2;              // d-tile 0..7
    const int k0 = (dq & 3) * 16;        // k within 64

    const size_t hbase = ((size_t)((mb256 * 16 + j) * 2 + half)) * 8192;       // shorts
    const size_t lbase = ((size_t)((mb256 * 16 + 8 + j) * 2 + half)) * 8192;

    #pragma unroll 2
    for (int p = 0; p < 16; ++p) {
        const int r  = p * 8 + rq;       // row in half-image 0..127
        const int gr = mb128 * 128 + r;  // global mean-row
        const float* a0 = ce + (size_t)(2 * gr) * D_DIM + d0;
        const float* a1 = a0 + D_DIM;
        float4 x0[4], x1[4];
        #pragma unroll
        for (int q = 0; q < 4; ++q) {
            x0[q] = *(const float4*)(a0 + q * 4);
            x1[q] = *(const float4*)(a1 + q * 4);
        }
        short8 h8[2], l8[2];
        #pragma unroll
        for (int q = 0; q < 4; ++q) {
            const float m[4] = {0.5f * (x0[q].x + x1[q].x), 0.5f * (x0[q].y + x1[q].y),
                                0.5f * (x0[q].z + x1[q].z), 0.5f * (x0[q].w + x1[q].w)};
            #pragma unroll
            for (int e = 0; e < 4; ++e) {
                unsigned short hh, ll;
                split_bf16(m[e], hh, ll);
                h8[q >> 1][(q & 1) * 4 + e] = (short)hh;
                l8[q >> 1][(q & 1) * 4 + e] = (short)ll;
            }
        }
        const int L1 = r * 128 + k0 * 2;          // byte offset, unswizzled
        const int S1 = SWZ(L1);
        const int S2 = SWZ(L1 + 16);
        *(short8*)(Ap + hbase + (S1 >> 1)) = h8[0];
        *(short8*)(Ap + hbase + (S2 >> 1)) = h8[1];
        *(short8*)(Ap + lbase + (S1 >> 1)) = l8[0];
        *(short8*)(Ap + lbase + (S2 >> 1)) = l8[1];
    }
}

// ---------------------------------------------------------------------------
// Kernel 2: pack B' images [colb 8][btile 16][half 2][swz [128][64]] + cb_sq;
// btile 0-7 = bh, 8-15 = bl. Block 0 zeros Sk / counter / loss.
// 64 blocks x 256 thr, 32 codes per block.
// ---------------------------------------------------------------------------
__global__ __launch_bounds__(256, 1)
void cra_pack_b(const float* __restrict__ cb,
                unsigned short* __restrict__ Bp,
                float* __restrict__ cb_sq,
                float* __restrict__ Sk,
                int* __restrict__ counter,
                float* __restrict__ loss_out)
{
    __shared__ float cbs[32 * D_DIM];    // 64 KB
    const int tid = threadIdx.x;
    const int c0  = blockIdx.x * 32;

    if (blockIdx.x == 0) {
        #pragma unroll
        for (int j = 0; j < 8; ++j) Sk[tid + j * 256] = 0.0f;
        if (tid == 0) { counter[0] = 0; loss_out[0] = 0.0f; }
    }

    {   // stage 32 codebook rows, coalesced float4
        const float4* src = (const float4*)(cb + (size_t)c0 * D_DIM);
        float4* dst = (float4*)cbs;
        #pragma unroll
        for (int k = 0; k < 16; ++k) dst[tid + k * 256] = src[tid + k * 256];
    }
    __syncthreads();

    if (tid < 32) {
        const float* r = cbs + tid * D_DIM;
        float s = 0.f;
        for (int d = 0; d < D_DIM; ++d) s = fmaf(r[d], r[d], s);
        cb_sq[c0 + tid] = s;
    }

    // pack: thread owns local row (tid>>3), elems dspan..dspan+63
    const int row   = tid >> 3;
    const int k     = c0 + row;
    const int colb  = k >> 8;            // 0..7 (256-col tiles)
    const int cc    = k & 255;
    const int halfB = cc >> 7;
    const int rB    = cc & 127;
    const int dspan = (tid & 7) * 64;
    #pragma unroll
    for (int g = 0; g < 8; ++g) {
        const int d  = dspan + g * 8;
        const int j  = d >> 6;           // d-tile 0..7
        const int kk = d & 63;
        short8 h8, l8;
        #pragma unroll
        for (int e = 0; e < 8; ++e) {
            unsigned short hh, ll;
            split_bf16(cbs[row * D_DIM + d + e], hh, ll);
            h8[e] = (short)hh; l8[e] = (short)ll;
        }
        const int S = SWZ(rB * 128 + kk * 2);
        *(short8*)(Bp + ((size_t)((colb * 16 + j) * 2 + halfB)) * 8192 + (S >> 1))     = h8;
        *(short8*)(Bp + ((size_t)((colb * 16 + 8 + j) * 2 + halfB)) * 8192 + (S >> 1)) = l8;
    }
}

// ---------------------------------------------------------------------------
// Kernel 3: Sk[k] = ||cb[k]@W^T + pb - cb[k]||^2, atomically accumulated
// (Sk zeroed by pack_b). 256 blocks = 64 code-blocks x 4 e-blocks.
// ---------------------------------------------------------------------------
__global__ __launch_bounds__(256, 1)
void cra_proj(const float* __restrict__ cb,
              const float* __restrict__ W,
              const float* __restrict__ pb,
              float* __restrict__ Sk)
{
    __shared__ float cbs[32 * D_DIM];    // 64 KB
    __shared__ float red[4 * 32];
    const int tid = threadIdx.x;
    const int cblock = blockIdx.x >> 2;
    const int eb     = blockIdx.x & 3;
    const int c0 = cblock * 32;

    {
        const float4* src = (const float4*)(cb + (size_t)c0 * D_DIM);
        float4* dst = (float4*)cbs;
        #pragma unroll
        for (int k = 0; k < 16; ++k) dst[tid + k * 256] = src[tid + k * 256];
    }
    __syncthreads();

    const int e  = eb * 128 + (tid >> 1);
    const int dh = (tid & 1) * 256;
    float acc[32];
    #pragma unroll
    for (int c = 0; c < 32; ++c) acc[c] = 0.f;
    const float4* wrow = (const float4*)(W + (size_t)e * D_DIM + dh);
    for (int dq = 0; dq < 64; ++dq) {
        const float4 wv = wrow[dq];
        #pragma unroll
        for (int c = 0; c < 32; ++c) {
            const float4 cv = *(const float4*)&cbs[c * D_DIM + dh + dq * 4];
            acc[c] += cv.x * wv.x + cv.y * wv.y + cv.z * wv.z + cv.w * wv.w;
        }
    }
    const float bias = pb[e];
    const int w = tid >> 6;
    #pragma unroll
    for (int c = 0; c < 32; ++c) {
        const float full = acc[c] + __shfl_xor(acc[c], 1);
        const float diff = full + bias - cbs[c * D_DIM + e];
        float v = (tid & 1) ? 0.f : diff * diff;
        #pragma unroll
        for (int off = 32; off > 0; off >>= 1) v += __shfl_down(v, off, 64);
        if ((tid & 63) == 0) red[w * 32 + c] = v;
    }
    __syncthreads();
    if (tid < 32)
        atomicAdd(&Sk[c0 + tid],
                  red[tid] + red[32 + tid] + red[64 + tid] + red[96 + tid]);
}

// ---------------------------------------------------------------------------
// Kernel 4: 256x256-tile double-buffered GEMM, counted vmcnt.
// 1024 blocks (128 mb x 8 colb, bijective XCD swizzle: nwg%8==0), 512 thr /
// 8 waves (2M x 4N), per-wave 128x64 = 8x4 of 16x16x32, BK=64, 24 K-tiles.
// Tile index t: t<8 -> ah*bh, 8<=t<16 -> al*bh, t>=16 -> ah*bl.
//   a_tile(t) = t<16 ? t : t-16   (atiles 0-7 ah, 8-15 al)
//   b_tile(t) = t<8  ? t : t-8    (btiles 0-7 bh, 8-15 bl)
// Same d-order accumulation as round 5 => identical scores.
// ---------------------------------------------------------------------------
__global__ __launch_bounds__(512, 2)
void cra_gemm(const unsigned short* __restrict__ Ap,
              const unsigned short* __restrict__ Bp,
              const float* __restrict__ cb_sq,
              float4* __restrict__ wsRed)           // [32768][8] {v1,i1,v2,i2}
{
    __shared__ __align__(16) char sMem[131072];     // 2 bufs x (A 32K + B 32K)

    const int tid  = threadIdx.x;
    const int bid  = blockIdx.x;
    const int wgid = (bid & 7) * 128 + (bid >> 3);  // bijective, nwg=1024
    const int mb   = wgid >> 3;          // 0..127
    const int colb = wgid & 7;           // 0..7
    const int rowBase = mb * 256;
    const int colBase = colb * 256;

    const int lane = tid & 63;
    const int w    = tid >> 6;           // wave 0..7
    const int wm   = w >> 2;             // 0..1  (M half)
    const int wn   = w & 3;              // 0..3  (N quarter)
    const int cid  = lane & 15;
    const int quad = lane >> 4;

    // per-lane runtime part of the swizzled frag byte offsets
    const int swzm = ((cid & 1) << 6) | (((cid >> 1) & 3) << 4);
    const int aRT  = (cid * 128 + quad * 16) ^ swzm;
    const int bRT  = ((((wn & 1) * 64 + cid) * 128) + quad * 16) ^ swzm;

    // stage pointers: per wave per instruction, 16 B/lane, 1 KB/wave/instr
    const char* AgBase = (const char*)Ap + (size_t)(mb * 16) * 32768 + w * 1024 + lane * 16;
    const char* BgBase = (const char*)Bp + (size_t)(colb * 16) * 32768 + w * 1024 + lane * 16;

    f32x4 acc[8][4];
    #pragma unroll
    for (int mi = 0; mi < 8; ++mi)
        #pragma unroll
        for (int ni = 0; ni < 4; ++ni) acc[mi][ni] = (f32x4)(0.f);

    // prologue: stage tile 0 -> buf0, tile 1 -> buf1 (8 DMA/wave each)
    #pragma unroll
    for (int p = 0; p < 2; ++p) {
        const char* ag = AgBase + (size_t)p * 32768;   // a_tile(p)=p, b_tile(p)=p
        const char* bg = BgBase + (size_t)p * 32768;
        char* la = sMem + p * 65536 + w * 1024;
        char* lb = la + 32768;
        #pragma unroll
        for (int jj = 0; jj < 4; ++jj) {
            dma16(ag + jj * 8192, la + jj * 8192);
            dma16(bg + jj * 8192, lb + jj * 8192);
        }
    }

    #pragma unroll 1
    for (int t = 0; t < 24; ++t) {
        const int p = t & 1;
        // counted wait: tile t+1's 8 loads (issued last iter) may stay in
        // flight; tile t's are complete after this. Last iter drains fully.
        if (t < 23) asm volatile("s_waitcnt vmcnt(8)\n\ts_barrier" ::: "memory");
        else        asm volatile("s_waitcnt vmcnt(0)\n\ts_barrier" ::: "memory");

        const char* sAh = sMem + p * 65536 + wm * 16384;
        const char* sBh = sMem + p * 65536 + 32768 + (wn >> 1) * 16384;

        #pragma unroll
        for (int ks = 0; ks < 2; ++ks) {
            short8 af[8], bf[4];
            #pragma unroll
            for (int mi = 0; mi < 8; ++mi)
                af[mi] = *(const short8*)(sAh + ((aRT ^ (ks << 6)) + mi * 2048));
            #pragma unroll
            for (int ni = 0; ni < 4; ++ni)
                bf[ni] = *(const short8*)(sBh + ((bRT ^ (ks << 6)) + ni * 2048));
            __builtin_amdgcn_s_setprio(1);
            #pragma unroll
            for (int mi = 0; mi < 8; ++mi)
                #pragma unroll
                for (int ni = 0; ni < 4; ++ni)
                    acc[mi][ni] = __builtin_amdgcn_mfma_f32_16x16x32_bf16(af[mi], bf[ni], acc[mi][ni], 0, 0, 0);
            __builtin_amdgcn_s_setprio(0);
        }

        // all of this wave's LDS reads have RETURNED before crossing the
        // barrier (lgkmcnt(0) inside the asm), so buf[p] is safe to overwrite.
        asm volatile("s_waitcnt lgkmcnt(0)\n\ts_barrier" ::: "memory");

        if (t + 2 < 24) {
            const int tn = t + 2;
            const int at = tn < 16 ? tn : tn - 16;
            const int bt = tn < 8 ? tn : tn - 8;
            const char* ag = AgBase + (size_t)at * 32768;
            const char* bg = BgBase + (size_t)bt * 32768;
            char* la = sMem + p * 65536 + w * 1024;
            char* lb = la + 32768;
            #pragma unroll
            for (int jj = 0; jj < 4; ++jj) {
                dma16(ag + jj * 8192, la + jj * 8192);
                dma16(bg + jj * 8192, lb + jj * 8192);
            }
        }
    }

    // ---- epilogue: score + top-2; C/D layout col=cid, row=quad*4+reg
    __syncthreads();                     // reuse LDS for reduction scratch
    float4* sRed = (float4*)sMem;        // [row 256][wn 4][slot 4] = 64 KB

    float cq[4];
    #pragma unroll
    for (int ni = 0; ni < 4; ++ni) cq[ni] = cb_sq[colBase + wn * 64 + ni * 16 + cid];

    #pragma unroll
    for (int mi = 0; mi < 8; ++mi) {
        #pragma unroll
        for (int reg = 0; reg < 4; ++reg) {
            float v1 = 3.4e38f, v2 = 3.4e38f;
            int   i1 = 0x7FFFFFFF, i2 = 0x7FFFFFFF;
            #pragma unroll
            for (int ni = 0; ni < 4; ++ni) {
                const float s = fmaf(-2.0f, acc[mi][ni][reg], cq[ni]);
                merge_cand(s, colBase + wn * 64 + ni * 16 + cid, v1, i1, v2, i2);
            }
            #pragma unroll
            for (int d = 1; d <= 2; d <<= 1) {
                float ov1 = __shfl_xor(v1, d); int oi1 = __shfl_xor(i1, d);
                float ov2 = __shfl_xor(v2, d); int oi2 = __shfl_xor(i2, d);
                merge_cand(ov1, oi1, v1, i1, v2, i2);
                merge_cand(ov2, oi2, v1, i1, v2, i2);
            }
            if ((cid & 3) == 0) {
                const int rl = wm * 128 + mi * 16 + quad * 4 + reg;
                sRed[(rl * 4 + wn) * 4 + (cid >> 2)] =
                    make_float4(v1, __int_as_float(i1), v2, __int_as_float(i2));
            }
        }
    }
    __syncthreads();
    if (tid < 256) {
        float v1 = 3.4e38f, v2 = 3.4e38f;
        int   i1 = 0x7FFFFFFF, i2 = 0x7FFFFFFF;
        #pragma unroll
        for (int e = 0; e < 16; ++e) {
            const float4 q = sRed[tid * 16 + e];
            merge_cand(q.x, __float_as_int(q.y), v1, i1, v2, i2);
            merge_cand(q.z, __float_as_int(q.w), v1, i1, v2, i2);
        }
        wsRed[(size_t)(rowBase + tid) * 8 + colb] =
            make_float4(v1, __int_as_float(i1), v2, __int_as_float(i2));
    }
}

// ---------------------------------------------------------------------------
// Kernel 5: merge 8 colblock results per row; write idx, flag ties, loss.
// ---------------------------------------------------------------------------
__global__ __launch_bounds__(256, 1)
void cra_merge(const float4* __restrict__ wsRed,
               const float* __restrict__ Sk,
               float* __restrict__ out_idx,
               float* __restrict__ out_loss,
               int* __restrict__ counter,
               int* __restrict__ flagRow,
               int2* __restrict__ flagI)
{
    __shared__ float sl[256];
    const int tid = threadIdx.x;
    const int r = blockIdx.x * 256 + tid;
    float v1 = 3.4e38f, v2 = 3.4e38f;
    int   i1 = 0x7FFFFFFF, i2 = 0x7FFFFFFF;
    #pragma unroll 4
    for (int cbk = 0; cbk < 8; ++cbk) {
        const float4 t = wsRed[(size_t)r * 8 + cbk];
        merge_cand(t.x, __float_as_int(t.y), v1, i1, v2, i2);
        merge_cand(t.z, __float_as_int(t.w), v1, i1, v2, i2);
    }
    out_idx[r] = (float)i1;
    if (v2 - v1 < EPS_GAP) {
        const int slot = atomicAdd(counter, 1);
        flagRow[slot] = r;
        flagI[slot] = make_int2(i1, i2);
    }
    sl[tid] = Sk[i1];
    __syncthreads();
    for (int s = 128; s > 0; s >>= 1) { if (tid < s) sl[tid] += sl[tid + s]; __syncthreads(); }
    if (tid == 0) atomicAdd(out_loss, sl[0] * LOSS_SCALE);
}

// ---------------------------------------------------------------------------
// Kernel 6: gather embeddings (overwrites the A' image region).
// ---------------------------------------------------------------------------
__global__ __launch_bounds__(256, 1)
void cra_gather(const float* __restrict__ out_idx,
                const float4* __restrict__ cb4,
                float4* __restrict__ out4)
{
    __shared__ int sidx[128];
    const int tid = threadIdx.x;
    const int rb = blockIdx.x * 128;
    if (tid < 128) sidx[tid] = (int)out_idx[rb + tid];
    __syncthreads();
    for (int j = tid; j < 128 * 128; j += 256) {
        const int row = j >> 7, q = j & 127;
        out4[(size_t)(rb + row) * 128 + q] = cb4[(size_t)sidx[row] * 128 + q];
    }
}

// ---------------------------------------------------------------------------
// Kernel 7: exact-f32 recheck of flagged rows' top-2 candidates.
// ---------------------------------------------------------------------------
__global__ __launch_bounds__(256, 1)
void cra_recheck(const float* __restrict__ ce,
                 const float* __restrict__ cb,
                 const float* __restrict__ cb_sq,
                 const float* __restrict__ Sk,
                 const int* __restrict__ counter,
                 const int* __restrict__ flagRow,
                 const int2* __restrict__ flagI,
                 float* __restrict__ out_idx,
                 float4* __restrict__ out4,
                 float* __restrict__ out_loss,
                 const float4* __restrict__ cb4)
{
    __shared__ float rp[8];
    __shared__ int swin;
    const int tid = threadIdx.x;
    const int n = counter[0];
    for (int f = blockIdx.x; f < n; f += 64) {
        const int row = flagRow[f];
        const int2 ii = flagI[f];
        const int d0 = tid * 2;
        const float2 x0 = *(const float2*)(ce + (size_t)(2 * row) * D_DIM + d0);
        const float2 x1 = *(const float2*)(ce + (size_t)(2 * row) * D_DIM + D_DIM + d0);
        const float m0 = 0.5f * (x0.x + x1.x), m1 = 0.5f * (x0.y + x1.y);
        const float* c1 = cb + (size_t)ii.x * D_DIM + d0;
        const float* c2 = cb + (size_t)ii.y * D_DIM + d0;
        float p1 = fmaf(m0, c1[0], m1 * c1[1]);
        float p2 = fmaf(m0, c2[0], m1 * c2[1]);
        #pragma unroll
        for (int off = 32; off > 0; off >>= 1) {
            p1 += __shfl_down(p1, off, 64);
            p2 += __shfl_down(p2, off, 64);
        }
        if ((tid & 63) == 0) { rp[(tid >> 6) * 2] = p1; rp[(tid >> 6) * 2 + 1] = p2; }
        __syncthreads();
        if (tid == 0) {
            const float dot1 = rp[0] + rp[2] + rp[4] + rp[6];
            const float dot2 = rp[1] + rp[3] + rp[5] + rp[7];
            const float s1 = cb_sq[ii.x] - 2.f * dot1;
            const float s2 = cb_sq[ii.y] - 2.f * dot2;
            const int win = (s2 < s1 || (s2 == s1 && ii.y < ii.x)) ? ii.y : ii.x;
            swin = win;
            if (win != ii.x) {
                out_idx[row] = (float)win;
                atomicAdd(out_loss, (Sk[win] - Sk[ii.x]) * LOSS_SCALE);
            }
        }
        __syncthreads();
        if (swin != ii.x) {
            for (int q = tid; q < 128; q += 256)
                out4[(size_t)row * 128 + q] = cb4[(size_t)swin * 128 + q];
        }
        __syncthreads();
    }
}

// ---------------------------------------------------------------------------
extern "C" void kernel_launch(void* const* d_in, const int* in_sizes, int n_in,
                              void* d_out, int out_size, void* d_ws, size_t ws_size,
                              hipStream_t stream)
{
    // inputs: 0 char_tokens (unused), 1 char_embeddings, 2 word_codebook,
    //         3 proj_w, 4 proj_b
    const float* ce = (const float*)d_in[1];
    const float* cb = (const float*)d_in[2];
    const float* W  = (const float*)d_in[3];
    const float* pb = (const float*)d_in[4];

    char* ws = (char*)d_ws;                                  // ~13 MB used
    unsigned short* Bp = (unsigned short*)ws;                // 4 MB B' images
    float4* wsRed  = (float4*)(ws + 4194304);                // 4 MB top-2 scratch
    float* cb_sq   = (float*)(ws + 12582912);
    float* Sk      = (float*)(ws + 12582912 + 8192);
    int*   flagRow = (int*)(ws + 12582912 + 16384);
    int2*  flagI   = (int2*)(ws + 12582912 + 16384 + 131072);
    int*   counter = (int*)(ws + 12582912 + 16384 + 131072 + 262144);

    float* out_idx  = (float*)d_out;
    float* out_emb  = out_idx + N_ROWS;
    float* out_loss = out_emb + (size_t)N_ROWS * D_DIM;
    // A' images (64 MiB exactly) live in the emb region until gather overwrites.
    unsigned short* Ap = (unsigned short*)out_emb;

    cra_pack_a<<<256, 256, 0, stream>>>(ce, Ap);
    cra_pack_b<<<64, 256, 0, stream>>>(cb, Bp, cb_sq, Sk, counter, out_loss);
    cra_proj<<<256, 256, 0, stream>>>(cb, W, pb, Sk);
    cra_gemm<<<1024, 512, 0, stream>>>(Ap, Bp, cb_sq, wsRed);
    cra_merge<<<128, 256, 0, stream>>>(wsRed, Sk, out_idx, out_loss, counter, flagRow, flagI);
    cra_gather<<<256, 256, 0, stream>>>(out_idx, (const float4*)cb, (float4*)out_emb);
    cra_recheck<<<64, 256, 0, stream>>>(ce, cb, cb_sq, Sk, counter, flagRow, flagI,
                                        out_idx, (float4*)out_emb, out_loss, (const float4*)cb);
}

// Round 2
// 932.431 us; speedup vs baseline: 1.0458x; 1.0458x over previous
//
#include <hip/hip_runtime.h>

// SimpleCRA round 7: round-5 structure (proven 598us gemm) + counted-vmcnt
// 3-buffer pipeline (T4). ONLY cra_gemm's staging/sync changed vs round 5:
//   - LDS 48 KB = 3 chunk buffers x (sA 8K + sB 8K); 3 blocks/CU (TLP kept)
//   - prologue stages chunks 0,1; iter g waits vmcnt(4) (chunk g landed,
//     chunk g+1 stays in flight), computes, lgkmcnt(0)+barrier, stages g+2
//     into buffer (g+2)%3. Loads fly for a full iteration+ instead of being
//     drained immediately (round 5's __syncthreads forced vmcnt(0)).
// Math identical to rounds 5/6: virtual-K split-bf16, dot = ah*bh + al*bh
// + ah*bl, K'=1536, same accumulation order => bitwise-identical scores;
// EPS/tie-recheck path unchanged. Pack/merge/gather/recheck = round 5 verbatim.

#define D_DIM    512
#define K_CODES  2048
#define N_ROWS   32768
#define EPS_GAP  1e-5f
#define LOSS_SCALE (1.0f / 16777216.0f)   // 1/(N_ROWS*D_DIM)

typedef __attribute__((ext_vector_type(8))) short short8;   // 8 bf16 (4 VGPR)
typedef __attribute__((ext_vector_type(4))) float f32x4;    // MFMA C/D

__device__ __forceinline__ void split_bf16(float f, unsigned short& h, unsigned short& l) {
    unsigned u = __float_as_uint(f);
    h = (unsigned short)(u >> 16);                       // truncation split
    float hr = __uint_as_float(u & 0xFFFF0000u);
    l = (unsigned short)(__float_as_uint(f - hr) >> 16);
}

// async global->LDS DMA, 16 B/lane; lds ptr wave-uniform, HW adds lane*16.
__device__ __forceinline__ void dma16(const void* g, void* l) {
    __builtin_amdgcn_global_load_lds(
        (const __attribute__((address_space(1))) unsigned int*)g,
        (__attribute__((address_space(3))) unsigned int*)l, 16, 0, 0);
}

// insert candidate into sorted-2 list ordered by (val, idx) — total order,
// merge-order independent; matches numpy first-occurrence argmin.
__device__ __forceinline__ void merge_cand(float s, int idx, float& v1, int& i1, float& v2, int& i2) {
    if (s < v1 || (s == v1 && idx < i1)) { v2 = v1; i2 = i1; v1 = s; i1 = idx; }
    else if (s < v2 || (s == v2 && idx < i2)) { v2 = s; i2 = idx; }
}

// ---------------------------------------------------------------------------
// Kernel 1: pack A' images. Block = one mb (128 mean-rows); layout
// [mb 256][ach 32][row 128][k 32] shorts, ach 0-15 = Ah, 16-31 = Al.
// ---------------------------------------------------------------------------
__global__ __launch_bounds__(256, 1)
void cra_pack_a(const float* __restrict__ ce,
                unsigned short* __restrict__ Ap)
{
    const int tid = threadIdx.x;
    const int mb  = blockIdx.x;
    const int rq  = tid >> 5;            // row slice 0..7
    const int dq  = tid & 31;            // 16-float span index
    const int dbase = dq * 16;
    const int ach = dq >> 1;             // 0..15
    const int k0  = (dq & 1) * 16;

    #pragma unroll 2
    for (int p = 0; p < 16; ++p) {
        const int r  = p * 8 + rq;       // 0..127
        const int gr = mb * 128 + r;
        const float* a0 = ce + (size_t)(2 * gr) * D_DIM + dbase;
        const float* a1 = a0 + D_DIM;
        float4 x0[4], x1[4];
        #pragma unroll
        for (int q = 0; q < 4; ++q) {
            x0[q] = *(const float4*)(a0 + q * 4);
            x1[q] = *(const float4*)(a1 + q * 4);
        }
        short8 h8[2], l8[2];
        #pragma unroll
        for (int q = 0; q < 4; ++q) {
            const float m[4] = {0.5f * (x0[q].x + x1[q].x), 0.5f * (x0[q].y + x1[q].y),
                                0.5f * (x0[q].z + x1[q].z), 0.5f * (x0[q].w + x1[q].w)};
            #pragma unroll
            for (int e = 0; e < 4; ++e) {
                unsigned short hh, ll;
                split_bf16(m[e], hh, ll);
                h8[q >> 1][(q & 1) * 4 + e] = (short)hh;
                l8[q >> 1][(q & 1) * 4 + e] = (short)ll;
            }
        }
        const size_t hb = ((size_t)(mb * 32 + ach) * 128 + r) * 32 + k0;
        const size_t lb = ((size_t)(mb * 32 + 16 + ach) * 128 + r) * 32 + k0;
        *(short8*)(Ap + hb)     = h8[0];
        *(short8*)(Ap + hb + 8) = h8[1];
        *(short8*)(Ap + lb)     = l8[0];
        *(short8*)(Ap + lb + 8) = l8[1];
    }
}

// ---------------------------------------------------------------------------
// Kernel 2: pack B' images [colb 16][bch 32][row 128][k 32] + cb_sq; block 0
// zeros Sk / counter / loss. 64 blocks x 256 thr, 32 codes per block.
// ---------------------------------------------------------------------------
__global__ __launch_bounds__(256, 1)
void cra_pack_b(const float* __restrict__ cb,
                unsigned short* __restrict__ Bp,
                float* __restrict__ cb_sq,
                float* __restrict__ Sk,
                int* __restrict__ counter,
                float* __restrict__ loss_out)
{
    __shared__ float cbs[32 * D_DIM];    // 64 KB
    const int tid = threadIdx.x;
    const int c0  = blockIdx.x * 32;

    if (blockIdx.x == 0) {
        #pragma unroll
        for (int j = 0; j < 8; ++j) Sk[tid + j * 256] = 0.0f;
        if (tid == 0) { counter[0] = 0; loss_out[0] = 0.0f; }
    }

    {   // stage 32 codebook rows, coalesced float4
        const float4* src = (const float4*)(cb + (size_t)c0 * D_DIM);
        float4* dst = (float4*)cbs;
        #pragma unroll
        for (int k = 0; k < 16; ++k) dst[tid + k * 256] = src[tid + k * 256];
    }
    __syncthreads();

    if (tid < 32) {
        const float* r = cbs + tid * D_DIM;
        float s = 0.f;
        for (int d = 0; d < D_DIM; ++d) s = fmaf(r[d], r[d], s);
        cb_sq[c0 + tid] = s;
    }

    // pack: thread owns local row (tid>>3), elems dspan..dspan+63
    const int row  = tid >> 3;
    const int k    = c0 + row;
    const int colb = k >> 7;             // 0..15
    const int pr   = k & 127;
    const int dspan = (tid & 7) * 64;
    #pragma unroll
    for (int g = 0; g < 8; ++g) {
        const int d   = dspan + g * 8;
        const int bch = d >> 5;
        const int k0  = d & 31;
        short8 h8, l8;
        #pragma unroll
        for (int e = 0; e < 8; ++e) {
            unsigned short hh, ll;
            split_bf16(cbs[row * D_DIM + d + e], hh, ll);
            h8[e] = (short)hh; l8[e] = (short)ll;
        }
        *(short8*)(Bp + ((size_t)(colb * 32 + bch) * 128 + pr) * 32 + k0)      = h8;
        *(short8*)(Bp + ((size_t)(colb * 32 + 16 + bch) * 128 + pr) * 32 + k0) = l8;
    }
}

// ---------------------------------------------------------------------------
// Kernel 3: Sk[k] = ||cb[k]@W^T + pb - cb[k]||^2, atomically accumulated
// (Sk zeroed by pack_b). 256 blocks = 64 code-blocks x 4 e-blocks.
// ---------------------------------------------------------------------------
__global__ __launch_bounds__(256, 1)
void cra_proj(const float* __restrict__ cb,
              const float* __restrict__ W,
              const float* __restrict__ pb,
              float* __restrict__ Sk)
{
    __shared__ float cbs[32 * D_DIM];    // 64 KB
    __shared__ float red[4 * 32];
    const int tid = threadIdx.x;
    const int cblock = blockIdx.x >> 2;
    const int eb     = blockIdx.x & 3;
    const int c0 = cblock * 32;

    {
        const float4* src = (const float4*)(cb + (size_t)c0 * D_DIM);
        float4* dst = (float4*)cbs;
        #pragma unroll
        for (int k = 0; k < 16; ++k) dst[tid + k * 256] = src[tid + k * 256];
    }
    __syncthreads();

    const int e  = eb * 128 + (tid >> 1);
    const int dh = (tid & 1) * 256;
    float acc[32];
    #pragma unroll
    for (int c = 0; c < 32; ++c) acc[c] = 0.f;
    const float4* wrow = (const float4*)(W + (size_t)e * D_DIM + dh);
    for (int dq = 0; dq < 64; ++dq) {
        const float4 wv = wrow[dq];
        #pragma unroll
        for (int c = 0; c < 32; ++c) {
            const float4 cv = *(const float4*)&cbs[c * D_DIM + dh + dq * 4];
            acc[c] += cv.x * wv.x + cv.y * wv.y + cv.z * wv.z + cv.w * wv.w;
        }
    }
    const float bias = pb[e];
    const int w = tid >> 6;
    #pragma unroll
    for (int c = 0; c < 32; ++c) {
        const float full = acc[c] + __shfl_xor(acc[c], 1);
        const float diff = full + bias - cbs[c * D_DIM + e];
        float v = (tid & 1) ? 0.f : diff * diff;
        #pragma unroll
        for (int off = 32; off > 0; off >>= 1) v += __shfl_down(v, off, 64);
        if ((tid & 63) == 0) red[w * 32 + c] = v;
    }
    __syncthreads();
    if (tid < 32)
        atomicAdd(&Sk[c0 + tid],
                  red[tid] + red[32 + tid] + red[64 + tid] + red[96 + tid]);
}

// ---------------------------------------------------------------------------
// Kernel 4: m97-template GEMM + counted-vmcnt 3-buffer pipeline.
// 4096 blocks (256 mb x 16 colb, XCD-swizzled), 256 thr / 4 waves, tile
// 128x128, wave 64x64 = 4x4 of 16x16x32, K' = 1536 (48 chunks of 32).
// LDS 48 KB (3 x 16 KB chunk buffers), 3 blocks/CU.
// ---------------------------------------------------------------------------
__global__ __launch_bounds__(256, 3)
void cra_gemm(const unsigned short* __restrict__ Ap,
              const unsigned short* __restrict__ Bp,
              const float* __restrict__ cb_sq,
              float4* __restrict__ wsRed)           // [32768][16] {v1,i1,v2,i2}
{
    __shared__ short sMem[3 * 8192];     // 48 KB: 3 x (sA 128x32 + sB 128x32)

    const int tid  = threadIdx.x;
    const int bid  = blockIdx.x;
    const int xcd  = bid & 7;
    const int slot = bid >> 3;           // 0..511
    const int mb   = xcd * 32 + (slot >> 4);
    const int colb = slot & 15;
    const int rowBase = mb * 128;
    const int colBase = colb * 128;

    const int lane = tid & 63;
    const int w    = tid >> 6;           // 0..3
    const int wr   = (w & 1) * 64;
    const int wcH  = w >> 1;             // 0..1
    const int wc   = wcH * 64;
    const int cid  = lane & 15;
    const int quad = lane >> 4;

    f32x4 acc[4][4];
    #pragma unroll
    for (int i = 0; i < 4; ++i)
        #pragma unroll
        for (int j = 0; j < 4; ++j) acc[i][j] = (f32x4)(0.f);

    // DMA geometry: chunk image = 8 KB contiguous; wave w covers 2 KB via
    // two 16B/lane instructions (A) + two (B).
    const char* Ag = (const char*)Ap + ((size_t)mb   * 32) * 8192 + w * 2048 + lane * 16;
    const char* Bg = (const char*)Bp + ((size_t)colb * 32) * 8192 + w * 2048 + lane * 16;

    auto stage = [&](int g, int p) {
        const int ach = g & 31;
        const int bch = (g & 15) | ((g & 32) >> 1);
        const char* ag = Ag + ach * 8192;
        const char* bg = Bg + bch * 8192;
        char* lA = (char*)sMem + p * 16384 + w * 2048;
        char* lB = lA + 8192;
        dma16(ag,        lA);
        dma16(ag + 1024, lA + 1024);
        dma16(bg,        lB);
        dma16(bg + 1024, lB + 1024);
    };

    // prologue: chunks 0,1 in flight before the loop
    stage(0, 0);
    stage(1, 1);

    int p  = 0;   // buffer holding chunk g
    int pn = 2;   // buffer for chunk g+2
    #pragma unroll 1
    for (int g = 0; g < 48; ++g) {
        // counted wait: chunk g+1's 4 loads stay in flight; chunk g's 4 are
        // the oldest and must land. All waves align at the barrier, so the
        // whole buffer (written by all 4 waves) is complete.
        if (g < 47) asm volatile("s_waitcnt vmcnt(4)\n\ts_barrier" ::: "memory");
        else        asm volatile("s_waitcnt vmcnt(0)\n\ts_barrier" ::: "memory");

        const short* sA = sMem + p * 8192;
        const short* sB = sA + 4096;

        short8 aF[4], bF[4];
        #pragma unroll
        for (int mi = 0; mi < 4; ++mi) aF[mi] = *(const short8*)&sA[(wr + mi * 16 + cid) * 32 + quad * 8];
        #pragma unroll
        for (int ni = 0; ni < 4; ++ni) bF[ni] = *(const short8*)&sB[(wc + ni * 16 + cid) * 32 + quad * 8];
        __builtin_amdgcn_s_setprio(1);
        #pragma unroll
        for (int mi = 0; mi < 4; ++mi)
            #pragma unroll
            for (int ni = 0; ni < 4; ++ni)
                acc[mi][ni] = __builtin_amdgcn_mfma_f32_16x16x32_bf16(aF[mi], bF[ni], acc[mi][ni], 0, 0, 0);
        __builtin_amdgcn_s_setprio(0);

        // this wave's LDS reads retired before crossing; after the barrier,
        // buffer (g-1)%3 is reusable block-wide.
        asm volatile("s_waitcnt lgkmcnt(0)\n\ts_barrier" ::: "memory");

        if (g + 2 < 48) stage(g + 2, pn);
        p  = (p  == 2) ? 0 : p  + 1;
        pn = (pn == 2) ? 0 : pn + 1;
    }

    // ---- epilogue: score + top-2; C/D layout col=lane&15, row=quad*4+reg
    float cq[4];
    #pragma unroll
    for (int ni = 0; ni < 4; ++ni) cq[ni] = cb_sq[colBase + wc + ni * 16 + cid];

    float4* sRed = (float4*)sMem;        // [row 128][wcH 2][slot 4] = 16 KB
    #pragma unroll
    for (int mi = 0; mi < 4; ++mi) {
        #pragma unroll
        for (int reg = 0; reg < 4; ++reg) {
            float v1 = 3.4e38f, v2 = 3.4e38f;
            int   i1 = 0x7FFFFFFF, i2 = 0x7FFFFFFF;
            #pragma unroll
            for (int ni = 0; ni < 4; ++ni) {
                const float s = fmaf(-2.0f, acc[mi][ni][reg], cq[ni]);
                merge_cand(s, colBase + wc + ni * 16 + cid, v1, i1, v2, i2);
            }
            #pragma unroll
            for (int d = 1; d <= 2; d <<= 1) {
                float ov1 = __shfl_xor(v1, d); int oi1 = __shfl_xor(i1, d);
                float ov2 = __shfl_xor(v2, d); int oi2 = __shfl_xor(i2, d);
                merge_cand(ov1, oi1, v1, i1, v2, i2);
                merge_cand(ov2, oi2, v1, i1, v2, i2);
            }
            if ((cid & 3) == 0) {
                const int row = wr + mi * 16 + quad * 4 + reg;
                sRed[(row * 2 + wcH) * 4 + (cid >> 2)] =
                    make_float4(v1, __int_as_float(i1), v2, __int_as_float(i2));
            }
        }
    }
    __syncthreads();
    if (tid < 128) {
        float v1 = 3.4e38f, v2 = 3.4e38f;
        int   i1 = 0x7FFFFFFF, i2 = 0x7FFFFFFF;
        #pragma unroll
        for (int e = 0; e < 8; ++e) {
            const float4 t = sRed[tid * 8 + e];
            merge_cand(t.x, __float_as_int(t.y), v1, i1, v2, i2);
            merge_cand(t.z, __float_as_int(t.w), v1, i1, v2, i2);
        }
        wsRed[(size_t)(rowBase + tid) * 16 + colb] =
            make_float4(v1, __int_as_float(i1), v2, __int_as_float(i2));
    }
}

// ---------------------------------------------------------------------------
// Kernel 5: merge 16 colblock results per row; write idx, flag ties, loss.
// ---------------------------------------------------------------------------
__global__ __launch_bounds__(256, 1)
void cra_merge(const float4* __restrict__ wsRed,
               const float* __restrict__ Sk,
               float* __restrict__ out_idx,
               float* __restrict__ out_loss,
               int* __restrict__ counter,
               int* __restrict__ flagRow,
               int2* __restrict__ flagI)
{
    __shared__ float sl[256];
    const int tid = threadIdx.x;
    const int r = blockIdx.x * 256 + tid;
    float v1 = 3.4e38f, v2 = 3.4e38f;
    int   i1 = 0x7FFFFFFF, i2 = 0x7FFFFFFF;
    #pragma unroll 4
    for (int cbk = 0; cbk < 16; ++cbk) {
        const float4 t = wsRed[(size_t)r * 16 + cbk];
        merge_cand(t.x, __float_as_int(t.y), v1, i1, v2, i2);
        merge_cand(t.z, __float_as_int(t.w), v1, i1, v2, i2);
    }
    out_idx[r] = (float)i1;
    if (v2 - v1 < EPS_GAP) {
        const int slot = atomicAdd(counter, 1);
        flagRow[slot] = r;
        flagI[slot] = make_int2(i1, i2);
    }
    sl[tid] = Sk[i1];
    __syncthreads();
    for (int s = 128; s > 0; s >>= 1) { if (tid < s) sl[tid] += sl[tid + s]; __syncthreads(); }
    if (tid == 0) atomicAdd(out_loss, sl[0] * LOSS_SCALE);
}

// ---------------------------------------------------------------------------
// Kernel 6: gather embeddings (overwrites the A' image region).
// ---------------------------------------------------------------------------
__global__ __launch_bounds__(256, 1)
void cra_gather(const float* __restrict__ out_idx,
                const float4* __restrict__ cb4,
                float4* __restrict__ out4)
{
    __shared__ int sidx[128];
    const int tid = threadIdx.x;
    const int rb = blockIdx.x * 128;
    if (tid < 128) sidx[tid] = (int)out_idx[rb + tid];
    __syncthreads();
    for (int j = tid; j < 128 * 128; j += 256) {
        const int row = j >> 7, q = j & 127;
        out4[(size_t)(rb + row) * 128 + q] = cb4[(size_t)sidx[row] * 128 + q];
    }
}

// ---------------------------------------------------------------------------
// Kernel 7: exact-f32 recheck of flagged rows' top-2 candidates.
// ---------------------------------------------------------------------------
__global__ __launch_bounds__(256, 1)
void cra_recheck(const float* __restrict__ ce,
                 const float* __restrict__ cb,
                 const float* __restrict__ cb_sq,
                 const float* __restrict__ Sk,
                 const int* __restrict__ counter,
                 const int* __restrict__ flagRow,
                 const int2* __restrict__ flagI,
                 float* __restrict__ out_idx,
                 float4* __restrict__ out4,
                 float* __restrict__ out_loss,
                 const float4* __restrict__ cb4)
{
    __shared__ float rp[8];
    __shared__ int swin;
    const int tid = threadIdx.x;
    const int n = counter[0];
    for (int f = blockIdx.x; f < n; f += 64) {
        const int row = flagRow[f];
        const int2 ii = flagI[f];
        const int d0 = tid * 2;
        const float2 x0 = *(const float2*)(ce + (size_t)(2 * row) * D_DIM + d0);
        const float2 x1 = *(const float2*)(ce + (size_t)(2 * row) * D_DIM + D_DIM + d0);
        const float m0 = 0.5f * (x0.x + x1.x), m1 = 0.5f * (x0.y + x1.y);
        const float* c1 = cb + (size_t)ii.x * D_DIM + d0;
        const float* c2 = cb + (size_t)ii.y * D_DIM + d0;
        float p1 = fmaf(m0, c1[0], m1 * c1[1]);
        float p2 = fmaf(m0, c2[0], m1 * c2[1]);
        #pragma unroll
        for (int off = 32; off > 0; off >>= 1) {
            p1 += __shfl_down(p1, off, 64);
            p2 += __shfl_down(p2, off, 64);
        }
        if ((tid & 63) == 0) { rp[(tid >> 6) * 2] = p1; rp[(tid >> 6) * 2 + 1] = p2; }
        __syncthreads();
        if (tid == 0) {
            const float dot1 = rp[0] + rp[2] + rp[4] + rp[6];
            const float dot2 = rp[1] + rp[3] + rp[5] + rp[7];
            const float s1 = cb_sq[ii.x] - 2.f * dot1;
            const float s2 = cb_sq[ii.y] - 2.f * dot2;
            const int win = (s2 < s1 || (s2 == s1 && ii.y < ii.x)) ? ii.y : ii.x;
            swin = win;
            if (win != ii.x) {
                out_idx[row] = (float)win;
                atomicAdd(out_loss, (Sk[win] - Sk[ii.x]) * LOSS_SCALE);
            }
        }
        __syncthreads();
        if (swin != ii.x) {
            for (int q = tid; q < 128; q += 256)
                out4[(size_t)row * 128 + q] = cb4[(size_t)swin * 128 + q];
        }
        __syncthreads();
    }
}

// ---------------------------------------------------------------------------
extern "C" void kernel_launch(void* const* d_in, const int* in_sizes, int n_in,
                              void* d_out, int out_size, void* d_ws, size_t ws_size,
                              hipStream_t stream)
{
    // inputs: 0 char_tokens (unused), 1 char_embeddings, 2 word_codebook,
    //         3 proj_w, 4 proj_b
    const float* ce = (const float*)d_in[1];
    const float* cb = (const float*)d_in[2];
    const float* W  = (const float*)d_in[3];
    const float* pb = (const float*)d_in[4];

    char* ws = (char*)d_ws;                                  // ~13 MB used
    unsigned short* Bp = (unsigned short*)ws;                // 4 MB B' images
    float4* wsRed  = (float4*)(ws + 4194304);                // 8 MB top-2 scratch
    float* cb_sq   = (float*)(ws + 12582912);
    float* Sk      = (float*)(ws + 12582912 + 8192);
    int*   flagRow = (int*)(ws + 12582912 + 16384);
    int2*  flagI   = (int2*)(ws + 12582912 + 16384 + 131072);
    int*   counter = (int*)(ws + 12582912 + 16384 + 131072 + 262144);

    float* out_idx  = (float*)d_out;
    float* out_emb  = out_idx + N_ROWS;
    float* out_loss = out_emb + (size_t)N_ROWS * D_DIM;
    // A' images (64 MiB) live in the emb output region until gather overwrites.
    unsigned short* Ap = (unsigned short*)out_emb;

    cra_pack_a<<<256, 256, 0, stream>>>(ce, Ap);
    cra_pack_b<<<64, 256, 0, stream>>>(cb, Bp, cb_sq, Sk, counter, out_loss);
    cra_proj<<<256, 256, 0, stream>>>(cb, W, pb, Sk);
    cra_gemm<<<4096, 256, 0, stream>>>(Ap, Bp, cb_sq, wsRed);
    cra_merge<<<128, 256, 0, stream>>>(wsRed, Sk, out_idx, out_loss, counter, flagRow, flagI);
    cra_gather<<<256, 256, 0, stream>>>(out_idx, (const float4*)cb, (float4*)out_emb);
    cra_recheck<<<64, 256, 0, stream>>>(ce, cb, cb_sq, Sk, counter, flagRow, flagI,
                                        out_idx, (float4*)out_emb, out_loss, (const float4*)cb);
}